// Round 12
// baseline (68.298 us; speedup 1.0000x reference)
//
#include <hip/hip_runtime.h>

#define NEG_SLOPE 0.1f

__device__ __forceinline__ float leaky(float v) { return v > 0.0f ? v : NEG_SLOPE * v; }

typedef _Float16 h4_t __attribute__((ext_vector_type(4)));
typedef _Float16 h8_t __attribute__((ext_vector_type(8)));
typedef float f32x4 __attribute__((ext_vector_type(4)));

__device__ __forceinline__ unsigned lds_off(const void* p) {
    return (unsigned)(unsigned long long)p;
}

__device__ __forceinline__ void lgkm0() {
    asm volatile("s_waitcnt lgkmcnt(0)" ::: "memory");
    __builtin_amdgcn_sched_barrier(0);        // rule #18
}

__device__ __forceinline__ h4_t tr16(unsigned addr) {
    h4_t d;
    asm volatile("ds_read_b64_tr_b16 %0, %1" : "=v"(d) : "v"(addr) : "memory");
    return d;
}

// ---------------------------------------------------------------------------
// PREP: W2T (fp16) + W1T (fp16) + tail-weight packing (K=16 A-frag order).
// wpack[r] (9216): [0,1024) w1 A-frags [fi];
//                  [1024,5120) w2 A-frags [fj][fi];
//                  [5120,9216) wp A-frags [gi][fj].
// A-frag (16x16x16): lane l, reg j holds W^T[m=l&15][k=(l>>4)*4+j].
// ---------------------------------------------------------------------------
__global__ __launch_bounds__(256) void prep_weights(const float* __restrict__ W2,
                                                    const float* __restrict__ W1,
                                                    const float* __restrict__ a1W,
                                                    const float* __restrict__ a2W,
                                                    const float* __restrict__ Wp2,
                                                    _Float16* __restrict__ W2T,
                                                    _Float16* __restrict__ W1T,
                                                    _Float16* __restrict__ wpack)
{
    __shared__ float tile[32][33];
    const int b   = blockIdx.x;
    const int tid = threadIdx.x;

    if (b < 1024) {                         // W2T[n][k] = fp16 W2[k][n]
        const int n0 = (b & 31) * 32, k0 = (b >> 5) * 32;
        const int r = tid >> 3, c4 = (tid & 7) * 4;
        float4 v = *reinterpret_cast<const float4*>(&W2[(size_t)(k0 + r) * 1024 + n0 + c4]);
        tile[r][c4 + 0] = v.x; tile[r][c4 + 1] = v.y;
        tile[r][c4 + 2] = v.z; tile[r][c4 + 3] = v.w;
        __syncthreads();
        h4_t o;
        o[0] = (_Float16)tile[c4 + 0][r]; o[1] = (_Float16)tile[c4 + 1][r];
        o[2] = (_Float16)tile[c4 + 2][r]; o[3] = (_Float16)tile[c4 + 3][r];
        *reinterpret_cast<h4_t*>(&W2T[(size_t)(n0 + r) * 1024 + k0 + c4]) = o;
    } else if (b < 1088) {                  // W1T[n][k] = fp16 W1[k][n]  (k<64)
        const int b2 = b - 1024;
        const int n0 = (b2 & 31) * 32, k0 = (b2 >> 5) * 32;
        const int r = tid >> 3, c4 = (tid & 7) * 4;
        float4 v = *reinterpret_cast<const float4*>(&W1[(size_t)(k0 + r) * 1024 + n0 + c4]);
        tile[r][c4 + 0] = v.x; tile[r][c4 + 1] = v.y;
        tile[r][c4 + 2] = v.z; tile[r][c4 + 3] = v.w;
        __syncthreads();
        h4_t o;
        o[0] = (_Float16)tile[c4 + 0][r]; o[1] = (_Float16)tile[c4 + 1][r];
        o[2] = (_Float16)tile[c4 + 2][r]; o[3] = (_Float16)tile[c4 + 3][r];
        *reinterpret_cast<h4_t*>(&W1T[(size_t)(n0 + r) * 64 + k0 + c4]) = o;
    } else {                                // pack tail weights (K=16 A-frag order)
        const int idx = (b - 1088) * 256 + tid;   // < 589824
        if (idx < 589824) {
            const int r = idx / 9216, qq = idx % 9216;
            float v;
            if (qq < 1024) {
                int fi = qq >> 8, rem = qq & 255, l = rem >> 2, j = rem & 3;
                int k = (l >> 4) * 4 + j, n = fi * 16 + (l & 15);
                v = a1W[(size_t)r * 1024 + k * 64 + n];
            } else if (qq < 5120) {
                int p = qq - 1024;
                int fj = p >> 10, fi = (p >> 8) & 3, rem = p & 255, l = rem >> 2, j = rem & 3;
                int k = fi * 16 + (l >> 4) * 4 + j, n = fj * 16 + (l & 15);
                v = a2W[(size_t)r * 4096 + k * 64 + n];
            } else {
                int p = qq - 5120;
                int gi = p >> 10, fj = (p >> 8) & 3, rem = p & 255, l = rem >> 2, j = rem & 3;
                int k = fj * 16 + (l >> 4) * 4 + j, n = gi * 16 + (l & 15);
                v = Wp2[((size_t)r * 64 + k) * 64 + n];
            }
            wpack[idx] = (_Float16)v;
        }
    }
}

// ---------------------------------------------------------------------------
// K1: split-K fp32 GEMM for t = x @ W_pca. Partials [8][4096][64].
// ---------------------------------------------------------------------------
__global__ __launch_bounds__(256) void gemm_n64_splitk(const float* __restrict__ A,
                                                       const float* __restrict__ B,
                                                       float* __restrict__ P)
{
    __shared__ alignas(16) float As[32][33];
    __shared__ alignas(16) float Bs[32][64];
    const int tid   = threadIdx.x;
    const int row0  = blockIdx.x * 32;
    const int kbase = blockIdx.y * 128;
    const int r0    = (tid >> 4) * 2;
    const int c0    = (tid & 15) * 4;
    const int am    = tid >> 3;
    const int ak    = (tid & 7) * 4;
    float acc[2][4] = {};

#pragma unroll
    for (int kc = 0; kc < 128; kc += 32) {
        const int k0 = kbase + kc;
        float4 va = *reinterpret_cast<const float4*>(&A[(size_t)(row0 + am) * 1024 + k0 + ak]);
        As[ak + 0][am] = va.x; As[ak + 1][am] = va.y;
        As[ak + 2][am] = va.z; As[ak + 3][am] = va.w;
#pragma unroll
        for (int p = 0; p < 2; ++p) {
            int idx = tid + p * 256;
            int kk  = idx >> 4;
            int nq  = (idx & 15) * 4;
            *reinterpret_cast<float4*>(&Bs[kk][nq]) =
                *reinterpret_cast<const float4*>(&B[(size_t)(k0 + kk) * 64 + nq]);
        }
        __syncthreads();
#pragma unroll
        for (int k = 0; k < 32; ++k) {
            float a0 = As[k][r0], a1 = As[k][r0 + 1];
            float4 bv = *reinterpret_cast<const float4*>(&Bs[k][c0]);
            acc[0][0] = fmaf(a0, bv.x, acc[0][0]); acc[0][1] = fmaf(a0, bv.y, acc[0][1]);
            acc[0][2] = fmaf(a0, bv.z, acc[0][2]); acc[0][3] = fmaf(a0, bv.w, acc[0][3]);
            acc[1][0] = fmaf(a1, bv.x, acc[1][0]); acc[1][1] = fmaf(a1, bv.y, acc[1][1]);
            acc[1][2] = fmaf(a1, bv.z, acc[1][2]); acc[1][3] = fmaf(a1, bv.w, acc[1][3]);
        }
        __syncthreads();
    }
#pragma unroll
    for (int i = 0; i < 2; ++i) {
        float4 o; o.x = acc[i][0]; o.y = acc[i][1]; o.z = acc[i][2]; o.w = acc[i][3];
        *reinterpret_cast<float4*>(
            &P[((size_t)blockIdx.y * 4096 + row0 + r0 + i) * 64 + c0]) = o;
    }
}

// K1b: t16 = fp16(sum_c P[c] + bias)
__global__ __launch_bounds__(256) void combine_t16(const float* __restrict__ P,
                                                   const float* __restrict__ bias,
                                                   _Float16* __restrict__ t16)
{
    const int idx = blockIdx.x * 256 + threadIdx.x;
    float s = bias[idx & 63];
#pragma unroll
    for (int c = 0; c < 8; ++c)
        s += P[(size_t)c * 262144 + idx];
    t16[idx] = (_Float16)s;
}

// ---------------------------------------------------------------------------
// K2: h1[4096][1024] = leaky(t16 @ W1 + b1) via fp16 MFMA (K=64). (unchanged)
// ---------------------------------------------------------------------------
__global__ __launch_bounds__(256) void gemm_k64_mfma(const _Float16* __restrict__ A,
                                                     const _Float16* __restrict__ BT,
                                                     const float* __restrict__ bias,
                                                     _Float16* __restrict__ C)
{
    __shared__ alignas(16) _Float16 As[128 * 64];
    __shared__ alignas(16) _Float16 Bs[128 * 64];
    const int tid = threadIdx.x;
    const int l   = tid & 63;
    const int w   = tid >> 6;
    const int wm  = w >> 1;
    const int wn  = w & 1;
    const int bm0 = blockIdx.y * 128;
    const int bn0 = blockIdx.x * 128;
    const int fr  = l & 15;
    const int fg  = l >> 4;
    const int srow  = l >> 3;
    const int sslot = l & 7;

#pragma unroll
    for (int i = 0; i < 4; ++i) {
        const int r0   = w * 32 + i * 8;
        const int rowA = r0 + srow;
        const int slot = sslot ^ (rowA & 7);
        __builtin_amdgcn_global_load_lds(
            (const __attribute__((address_space(1))) void*)&A[(size_t)(bm0 + rowA) * 64 + slot * 8],
            (__attribute__((address_space(3))) void*)&As[r0 * 64], 16, 0, 0);
        __builtin_amdgcn_global_load_lds(
            (const __attribute__((address_space(1))) void*)&BT[(size_t)(bn0 + rowA) * 64 + slot * 8],
            (__attribute__((address_space(3))) void*)&Bs[r0 * 64], 16, 0, 0);
    }
    __syncthreads();

    f32x4 acc[4][4] = {};
#pragma unroll
    for (int ks = 0; ks < 2; ++ks) {
        h8_t af[4], bf[4];
#pragma unroll
        for (int mt = 0; mt < 4; ++mt) {
            int row = wm * 64 + mt * 16 + fr;
            int sg  = ks * 4 + fg;
            af[mt] = *reinterpret_cast<const h8_t*>(&As[row * 64 + ((sg ^ (row & 7)) << 3)]);
        }
#pragma unroll
        for (int nt = 0; nt < 4; ++nt) {
            int row = wn * 64 + nt * 16 + fr;
            int sg  = ks * 4 + fg;
            bf[nt] = *reinterpret_cast<const h8_t*>(&Bs[row * 64 + ((sg ^ (row & 7)) << 3)]);
        }
#pragma unroll
        for (int mt = 0; mt < 4; ++mt)
#pragma unroll
            for (int nt = 0; nt < 4; ++nt)
                acc[mt][nt] = __builtin_amdgcn_mfma_f32_16x16x32_f16(af[mt], bf[nt],
                                                                     acc[mt][nt], 0, 0, 0);
    }

#pragma unroll
    for (int nt = 0; nt < 4; ++nt) {
        const int col = bn0 + wn * 64 + nt * 16 + fr;
        const float bv = bias[col];
#pragma unroll
        for (int mt = 0; mt < 4; ++mt)
#pragma unroll
            for (int rg = 0; rg < 4; ++rg) {
                const int row = bm0 + wm * 64 + mt * 16 + fg * 4 + rg;
                float v = acc[mt][nt][rg] + bv;
                C[(size_t)row * 1024 + col] = (_Float16)fmaxf(v, NEG_SLOPE * v);
            }
    }
}

// ---------------------------------------------------------------------------
// K3 v2: h2t = pack(leaky(h1 @ W2 + b2)). (unchanged from round 11)
// ---------------------------------------------------------------------------
__global__ __launch_bounds__(256) void gemm_mfma_f16_v2(const _Float16* __restrict__ A,
                                                        const _Float16* __restrict__ BT,
                                                        const float* __restrict__ bias,
                                                        _Float16* __restrict__ h2t)
{
    __shared__ alignas(16) _Float16 As[64 * 64];
    __shared__ alignas(16) _Float16 Bs[128 * 64];
    const int tid = threadIdx.x;
    const int l   = tid & 63;
    const int w   = tid >> 6;
    const int wm  = w >> 1;
    const int wn  = w & 1;
    const int bm0 = blockIdx.y * 64;
    const int bn0 = blockIdx.x * 128;
    const int fr  = l & 15;
    const int fg  = l >> 4;
    const int srow  = l >> 3;
    const int sslot = l & 7;

    f32x4 acc[2][4] = {};

    for (int k0 = 0; k0 < 1024; k0 += 64) {
#pragma unroll
        for (int i = 0; i < 2; ++i) {
            const int r0   = w * 16 + i * 8;
            const int rowA = r0 + srow;
            const int slot = sslot ^ (rowA & 7);
            __builtin_amdgcn_global_load_lds(
                (const __attribute__((address_space(1))) void*)&A[(size_t)(bm0 + rowA) * 1024 + k0 + slot * 8],
                (__attribute__((address_space(3))) void*)&As[r0 * 64], 16, 0, 0);
        }
#pragma unroll
        for (int i = 0; i < 4; ++i) {
            const int r0   = w * 32 + i * 8;
            const int rowB = r0 + srow;
            const int slot = sslot ^ (rowB & 7);
            __builtin_amdgcn_global_load_lds(
                (const __attribute__((address_space(1))) void*)&BT[(size_t)(bn0 + rowB) * 1024 + k0 + slot * 8],
                (__attribute__((address_space(3))) void*)&Bs[r0 * 64], 16, 0, 0);
        }
        __syncthreads();

#pragma unroll
        for (int ks = 0; ks < 2; ++ks) {
            h8_t af[2], bf[4];
#pragma unroll
            for (int mt = 0; mt < 2; ++mt) {
                int row = wm * 32 + mt * 16 + fr;
                int sg  = ks * 4 + fg;
                af[mt] = *reinterpret_cast<const h8_t*>(&As[row * 64 + ((sg ^ (row & 7)) << 3)]);
            }
#pragma unroll
            for (int nt = 0; nt < 4; ++nt) {
                int row = wn * 64 + nt * 16 + fr;
                int sg  = ks * 4 + fg;
                bf[nt] = *reinterpret_cast<const h8_t*>(&Bs[row * 64 + ((sg ^ (row & 7)) << 3)]);
            }
#pragma unroll
            for (int mt = 0; mt < 2; ++mt)
#pragma unroll
                for (int nt = 0; nt < 4; ++nt)
                    acc[mt][nt] = __builtin_amdgcn_mfma_f32_16x16x32_f16(af[mt], bf[nt],
                                                                         acc[mt][nt], 0, 0, 0);
        }
        __syncthreads();
    }

    const int rblk0 = (bm0 >> 4) + wm * 2;
    const int cblk0 = (bn0 >> 4) + wn * 4;
#pragma unroll
    for (int nt = 0; nt < 4; ++nt) {
        const int col = bn0 + wn * 64 + nt * 16 + fr;
        const float bv = bias[col];
#pragma unroll
        for (int mt = 0; mt < 2; ++mt) {
            h4_t pk;
#pragma unroll
            for (int r = 0; r < 4; ++r) {
                float v = acc[mt][nt][r] + bv;
                pk[r] = (_Float16)fmaxf(v, NEG_SLOPE * v);
            }
            *reinterpret_cast<h4_t*>(
                &h2t[(((size_t)(cblk0 + nt) * 256 + rblk0 + mt) * 16 + fr) * 16 + fg * 4]) = pk;
        }
    }
}

// ---------------------------------------------------------------------------
// K4: fused additive chain v6 — transposed all-register chain.
// aT = W1rT·hT; a2T = W2rT·aT; t2T += WpT·a2T. D-regs of each phase ARE the
// B-frag of the next (16x16x16 C/D layout == B layout). No act LDS, one
// lgkm0 per r (the h tr16s). Weights = A-frags via plain ds_read.
// Grid (32,16), 2 tiles/wave, LDS 44KB. Partials TRANSPOSED: [chunk][f][row].
// ---------------------------------------------------------------------------
#define RCH 4

__global__ __launch_bounds__(256) void fused_tail6(const _Float16* __restrict__ h2t,
                                                   const _Float16* __restrict__ wpack,
                                                   const float* __restrict__ a1b,
                                                   const float* __restrict__ a1bias,
                                                   const float* __restrict__ a2b,
                                                   const float* __restrict__ a2bias,
                                                   float* __restrict__ partials)
{
    __shared__ alignas(16) _Float16 stage[2][11264];  // 2 x 22KB

    const int tid = threadIdx.x;
    const int l = tid & 63, w = tid >> 6;
    const int c = l & 15, q = l >> 4;
    const int row0  = blockIdx.x * 128;
    const int rbase = blockIdx.y * RCH;
    const float b1s = a1bias[0], b2s = a2bias[0];

    const unsigned trl = l * 8;

    auto STAGE = [&](int rl, int b) {
        const int r = rbase + rl;
        const _Float16* hsrc = h2t + ((size_t)r * 256 + blockIdx.x * 8) * 256;
        const _Float16* wsrc = wpack + (size_t)r * 9216;
#pragma unroll
        for (int i = 0; i < 6; ++i) {
            const int ch = i * 4 + w;
            if (ch < 22) {
                const _Float16* src = (ch < 4) ? (hsrc + ch * 512) : (wsrc + (ch - 4) * 512);
                __builtin_amdgcn_global_load_lds(
                    (const __attribute__((address_space(1))) void*)(src + l * 8),
                    (__attribute__((address_space(3))) void*)&stage[b][ch * 512], 16, 0, 0);
            }
        }
    };

    STAGE(0, 0);
    __syncthreads();

    f32x4 accT[2][4] = {};   // [tile j][gi] : t2T, col=row-idx, row=f
    int cur = 0;

#pragma unroll
    for (int rl = 0; rl < RCH; ++rl) {
        const int r = rbase + rl;
        if (rl + 1 < RCH) STAGE(rl + 1, cur ^ 1);

        // biases for this r (off critical path: issued now, used post-MFMA)
        float4 b1f[4], b2f[4];
#pragma unroll
        for (int fi = 0; fi < 4; ++fi) {
            b1f[fi] = *reinterpret_cast<const float4*>(&a1b[r * 64 + fi * 16 + q * 4]);
            b2f[fi] = *reinterpret_cast<const float4*>(&a2b[r * 64 + fi * 16 + q * 4]);
        }

        const _Float16* sp = &stage[cur][0];
        const unsigned sbytes = lds_off(sp);

        // hT fragments (B-frag): tile w and w+4
        h4_t hf0 = tr16(sbytes + (unsigned)w * 512 + trl);
        h4_t hf1 = tr16(sbytes + (unsigned)(w + 4) * 512 + trl);
        lgkm0();

        // ---- phase A: aT[j][fi] = leaky(W1rT[fi] · hT[j] + b1)
        h4_t aT[2][4];
#pragma unroll
        for (int fi = 0; fi < 4; ++fi) {
            h4_t wf = *reinterpret_cast<const h4_t*>(&sp[2048 + fi * 256 + l * 4]);
            f32x4 p0 = __builtin_amdgcn_mfma_f32_16x16x16f16(wf, hf0, (f32x4){0.f,0.f,0.f,0.f}, 0, 0, 0);
            f32x4 p1 = __builtin_amdgcn_mfma_f32_16x16x16f16(wf, hf1, (f32x4){0.f,0.f,0.f,0.f}, 0, 0, 0);
#pragma unroll
            for (int rg = 0; rg < 4; ++rg) {
                float bb = reinterpret_cast<const float*>(&b1f[fi])[rg] + b1s;
                float v0 = p0[rg] + bb;
                float v1 = p1[rg] + bb;
                aT[0][fi][rg] = (_Float16)fmaxf(v0, NEG_SLOPE * v0);
                aT[1][fi][rg] = (_Float16)fmaxf(v1, NEG_SLOPE * v1);
            }
        }

        // ---- phase B: a2T[j][fj] = leaky(sum_fi W2rT[fj][fi] · aT[j][fi] + b2)
        h4_t a2T[2][4];
#pragma unroll
        for (int fj = 0; fj < 4; ++fj) {
            f32x4 p0 = {0.f,0.f,0.f,0.f}, p1 = {0.f,0.f,0.f,0.f};
#pragma unroll
            for (int fi = 0; fi < 4; ++fi) {
                h4_t wf = *reinterpret_cast<const h4_t*>(&sp[3072 + (fj * 4 + fi) * 256 + l * 4]);
                p0 = __builtin_amdgcn_mfma_f32_16x16x16f16(wf, aT[0][fi], p0, 0, 0, 0);
                p1 = __builtin_amdgcn_mfma_f32_16x16x16f16(wf, aT[1][fi], p1, 0, 0, 0);
            }
#pragma unroll
            for (int rg = 0; rg < 4; ++rg) {
                float bb = reinterpret_cast<const float*>(&b2f[fj])[rg] + b2s;
                float v0 = p0[rg] + bb;
                float v1 = p1[rg] + bb;
                a2T[0][fj][rg] = (_Float16)fmaxf(v0, NEG_SLOPE * v0);
                a2T[1][fj][rg] = (_Float16)fmaxf(v1, NEG_SLOPE * v1);
            }
        }

        // ---- phase C: t2T[j][gi] += sum_fj WpT[gi][fj] · a2T[j][fj]
#pragma unroll
        for (int gi = 0; gi < 4; ++gi)
#pragma unroll
            for (int fj = 0; fj < 4; ++fj) {
                h4_t wf = *reinterpret_cast<const h4_t*>(&sp[7168 + (gi * 4 + fj) * 256 + l * 4]);
                accT[0][gi] = __builtin_amdgcn_mfma_f32_16x16x16f16(wf, a2T[0][fj], accT[0][gi], 0, 0, 0);
                accT[1][gi] = __builtin_amdgcn_mfma_f32_16x16x16f16(wf, a2T[1][fj], accT[1][gi], 0, 0, 0);
            }

        __syncthreads();   // drains vmcnt for next stage + frees stage[cur]
        cur ^= 1;
    }

    // partials (transposed): [chunk][f(64)][row(4096)]
#pragma unroll
    for (int j = 0; j < 2; ++j) {
        const int row = row0 + (w + 4 * j) * 16 + c;
#pragma unroll
        for (int gi = 0; gi < 4; ++gi)
#pragma unroll
            for (int rg = 0; rg < 4; ++rg)
                partials[((size_t)blockIdx.y * 64 + gi * 16 + q * 4 + rg) * 4096 + row] =
                    accT[j][gi][rg];
    }
}

// ---------------------------------------------------------------------------
// K5: reduce 16 transposed partials + bp2, dot with Wl, add bl -> out[4096]
// 256 thr = 4 waves; wave w handles features w*16..w*16+15 for 64 rows.
// ---------------------------------------------------------------------------
__global__ __launch_bounds__(256) void reduce_out_t(const float* __restrict__ partials,
                                                    const float* __restrict__ bp2,
                                                    const float* __restrict__ Wl,
                                                    const float* __restrict__ bl,
                                                    float* __restrict__ out)
{
    __shared__ float red[4][64];
    const int tid  = threadIdx.x;
    const int w    = tid >> 6;
    const int lane = tid & 63;
    const int row  = blockIdx.x * 64 + lane;
    float s = 0.f;
#pragma unroll
    for (int f = w * 16; f < w * 16 + 16; ++f) {
        float v = bp2[f];
#pragma unroll
        for (int c = 0; c < 16; ++c)
            v += partials[((size_t)c * 64 + f) * 4096 + row];
        s += v * Wl[f];
    }
    red[w][lane] = s;
    __syncthreads();
    if (w == 0)
        out[row] = red[0][lane] + red[1][lane] + red[2][lane] + red[3][lane] + bl[0];
}

// ---------------------------------------------------------------------------
extern "C" void kernel_launch(void* const* d_in, const int* in_sizes, int n_in,
                              void* d_out, int out_size, void* d_ws, size_t ws_size,
                              hipStream_t stream)
{
    const float* x      = (const float*)d_in[0];
    const float* Wpca   = (const float*)d_in[1];
    const float* bpca   = (const float*)d_in[2];
    const float* W1     = (const float*)d_in[3];
    const float* b1     = (const float*)d_in[4];
    const float* W2     = (const float*)d_in[5];
    const float* b2     = (const float*)d_in[6];
    const float* a1W    = (const float*)d_in[7];
    const float* a1b    = (const float*)d_in[8];
    const float* a1bias = (const float*)d_in[9];
    const float* a2W    = (const float*)d_in[10];
    const float* a2b    = (const float*)d_in[11];
    const float* a2bias = (const float*)d_in[12];
    const float* Wp2    = (const float*)d_in[13];
    const float* bp2    = (const float*)d_in[14];
    const float* Wl     = (const float*)d_in[15];
    const float* bl     = (const float*)d_in[16];
    float* out = (float*)d_out;

    // workspace layout (bytes) — verified non-overlapping:
    //   t16 [0,0.5M)  h1h [1M,9M)  h2t [9M,17M)  W2T [17M,19M)
    //   wpack [19M,20.13M)  W1T [21M,21.13M)  partials [22M,38.8M)
    char* wsb = (char*)d_ws;
    _Float16* t16      = (_Float16*)(wsb);
    _Float16* h1h      = (_Float16*)(wsb + (1ull  << 20));
    _Float16* h2t      = (_Float16*)(wsb + (9ull  << 20));
    _Float16* W2T      = (_Float16*)(wsb + (17ull << 20));
    _Float16* wpack    = (_Float16*)(wsb + (19ull << 20));
    _Float16* W1T      = (_Float16*)(wsb + (21ull << 20));
    float*    partials = (float*)   (wsb + (22ull << 20));
    float*    tpart    = (float*)   (wsb + (9ull  << 20));   // aliases h2t (dead then)

    // prep: W2T + W1T + wpack in one launch
    prep_weights<<<dim3(3392), 256, 0, stream>>>(W2, W1, a1W, a2W, Wp2, W2T, W1T, wpack);
    // t = x @ W_pca + b_pca  (split-K fp32, combine -> fp16)
    gemm_n64_splitk<<<dim3(128, 8), 256, 0, stream>>>(x, Wpca, tpart);
    combine_t16<<<dim3(1024), 256, 0, stream>>>(tpart, bpca, t16);
    // h1 = leaky(t @ W1 + b1) via MFMA (K=64) -> linear fp16
    gemm_k64_mfma<<<dim3(8, 32), 256, 0, stream>>>(t16, W1T, b1, h1h);
    // h2 (packed) = leaky(h1 @ W2 + b2) via MFMA  (v2)
    gemm_mfma_f16_v2<<<dim3(8, 64), 256, 0, stream>>>(h1h, W2T, b2, h2t);
    // fused additive chain (transposed register chain) -> transposed partials
    fused_tail6<<<dim3(32, 16), 256, 0, stream>>>(h2t, wpack, a1b, a1bias,
                                                  a2b, a2bias, partials);
    // reduce partials + PCA2 bias + last layer
    reduce_out_t<<<dim3(64), 256, 0, stream>>>(partials, bp2, Wl, bl, out);
}